// Round 4
// baseline (318.112 us; speedup 1.0000x reference)
//
#include <hip/hip_runtime.h>

#define DIM 128
#define NPASS 8

typedef short bf16x8 __attribute__((ext_vector_type(8)));
typedef float f32x4  __attribute__((ext_vector_type(4)));

__device__ inline unsigned short f2b(float f) {  // fp32 -> bf16 RNE
  unsigned int u = __float_as_uint(f);
  unsigned int r = u + 0x7FFFu + ((u >> 16) & 1u);
  return (unsigned short)(r >> 16);
}

// ================= W -> bf16 convert (once per launch) =====================
__global__ __launch_bounds__(256) void conv_W(const float* __restrict__ W,
                                              unsigned short* __restrict__ Wb) {
  int i = blockIdx.x * 256 + threadIdx.x;
  if (i < DIM * DIM) Wb[i] = f2b(W[i]);
}

// ================= GEMM: hb = bf16(x @ W^T + b), MFMA ======================
__global__ __launch_bounds__(256) void gemm_mfma(
    const float* __restrict__ x, const unsigned short* __restrict__ Wb,
    const float* __restrict__ b, unsigned short* __restrict__ hb, int N) {
  const int wid  = threadIdx.x >> 6;
  const int lane = threadIdx.x & 63;
  const int m0   = blockIdx.x * 64 + wid * 16;
  const int mrow = m0 + (lane & 15);
  const int koff = (lane >> 4) * 8;
  const int arow = (mrow < N) ? mrow : 0;

  f32x4 acc[8];
#pragma unroll
  for (int j = 0; j < 8; ++j) acc[j] = (f32x4){0.f, 0.f, 0.f, 0.f};

#pragma unroll
  for (int k0 = 0; k0 < DIM; k0 += 32) {
    const float* xp = x + (size_t)arow * DIM + k0 + koff;
    float4 a0 = *reinterpret_cast<const float4*>(xp);
    float4 a1 = *reinterpret_cast<const float4*>(xp + 4);
    bf16x8 af;
    af[0] = (short)f2b(a0.x); af[1] = (short)f2b(a0.y);
    af[2] = (short)f2b(a0.z); af[3] = (short)f2b(a0.w);
    af[4] = (short)f2b(a1.x); af[5] = (short)f2b(a1.y);
    af[6] = (short)f2b(a1.z); af[7] = (short)f2b(a1.w);
#pragma unroll
    for (int j = 0; j < 8; ++j) {
      const unsigned short* wp = Wb + (size_t)(j * 16 + (lane & 15)) * DIM + k0 + koff;
      bf16x8 bf = *reinterpret_cast<const bf16x8*>(wp);
      acc[j] = __builtin_amdgcn_mfma_f32_16x16x32_bf16(af, bf, acc[j], 0, 0, 0);
    }
  }

  const int rowbase = (lane >> 4) * 4;
#pragma unroll
  for (int j = 0; j < 8; ++j) {
    int n = j * 16 + (lane & 15);
    float bias = b[n];
#pragma unroll
    for (int i = 0; i < 4; ++i) {
      int m = m0 + rowbase + i;
      if (m < N) hb[(size_t)m * DIM + n] = f2b(acc[j][i] + bias);
    }
  }
}

// ======================= CSR build (device-side) ===========================
__global__ __launch_bounds__(256) void hist_rows(const int* __restrict__ erow,
                                                 int* __restrict__ deg, int E) {
  int e = blockIdx.x * 256 + threadIdx.x;
  if (e < E) atomicAdd(&deg[erow[e]], 1);
}

__global__ __launch_bounds__(256) void scan_blocks(const int* __restrict__ deg,
                                                   int* __restrict__ off,
                                                   int* __restrict__ bsum, int N) {
  __shared__ int lds[256];
  const int base = blockIdx.x * 1024;
  const int t = threadIdx.x;
  int v[4], s = 0;
#pragma unroll
  for (int i = 0; i < 4; ++i) {
    int idx = base + t * 4 + i;
    v[i] = (idx < N) ? deg[idx] : 0;
    s += v[i];
  }
  lds[t] = s;
  __syncthreads();
  for (int d = 1; d < 256; d <<= 1) {
    int val = (t >= d) ? lds[t - d] : 0;
    __syncthreads();
    lds[t] += val;
    __syncthreads();
  }
  int incl = lds[t];
  int excl = incl - s;
  if (t == 255) bsum[blockIdx.x] = incl;
  int run = excl;
#pragma unroll
  for (int i = 0; i < 4; ++i) {
    int idx = base + t * 4 + i;
    if (idx < N) off[idx] = run;
    run += v[i];
  }
}

__global__ __launch_bounds__(256) void scan_bsum(int* __restrict__ bsum, int NB) {
  __shared__ int lds[256];
  const int t = threadIdx.x;
  int s = (t < NB) ? bsum[t] : 0;
  lds[t] = s;
  __syncthreads();
  for (int d = 1; d < 256; d <<= 1) {
    int val = (t >= d) ? lds[t - d] : 0;
    __syncthreads();
    lds[t] += val;
    __syncthreads();
  }
  if (t < NB) bsum[t] = lds[t] - s;  // exclusive
}

__global__ __launch_bounds__(256) void add_base(int* __restrict__ off,
                                                int* __restrict__ pos,
                                                const int* __restrict__ bsum, int N) {
  int i = blockIdx.x * 256 + threadIdx.x;
  if (i < N) {
    int o = off[i] + bsum[i >> 10];
    off[i] = o;
    pos[i] = o;
  }
}

// Range-filtered CSR placement: only edges with row in [lo,hi).
// Active sedge window per pass ~ E/NPASS*8B ~ 1.6MB -> L2-resident, full-line
// writebacks instead of 8x partial-line amplification.
__global__ __launch_bounds__(256) void scatter_csr_pass(
    const int* __restrict__ erow, const int* __restrict__ ecol,
    const float* __restrict__ ew, int* __restrict__ pos,
    int2* __restrict__ sedge, int E, int lo, int hi) {
  int e = blockIdx.x * 256 + threadIdx.x;
  if (e < E) {
    int r = erow[e];
    if (r >= lo && r < hi) {
      int p = atomicAdd(&pos[r], 1);
      sedge[p] = make_int2(ecol[e], __float_as_int(ew[e]));
    }
  }
}

// ============ Aggregate: out = lrelu(x + sum_e w*hb[col]) ==================
__global__ __launch_bounds__(256) void aggregate(
    const unsigned short* __restrict__ hb, const float* __restrict__ x,
    const int* __restrict__ off, const int* __restrict__ deg,
    const int2* __restrict__ sedge, float* __restrict__ out, int N) {
  int r = (blockIdx.x * 256 + threadIdx.x) >> 6;
  int lane = threadIdx.x & 63;
  if (r >= N) return;

  const int start = off[r];
  const int n = deg[r];
  float2 acc = make_float2(0.f, 0.f);
#pragma unroll 4
  for (int i = 0; i < n; ++i) {
    int2 e = sedge[start + i];
    float w = __int_as_float(e.y);
    unsigned int hv = *reinterpret_cast<const unsigned int*>(
        hb + (size_t)e.x * DIM + lane * 2);
    float h0 = __uint_as_float((hv & 0xFFFFu) << 16);
    float h1 = __uint_as_float((hv >> 16) << 16);
    acc.x += w * h0;
    acc.y += w * h1;
  }
  float2 xv = *reinterpret_cast<const float2*>(x + (size_t)r * DIM + lane * 2);
  float2 o = make_float2(acc.x + xv.x, acc.y + xv.y);
  o.x = o.x > 0.f ? o.x : 0.2f * o.x;
  o.y = o.y > 0.f ? o.y : 0.2f * o.y;
  *reinterpret_cast<float2*>(out + (size_t)r * DIM + lane * 2) = o;
}

// ===========================================================================
extern "C" void kernel_launch(void* const* d_in, const int* in_sizes, int n_in,
                              void* d_out, int out_size, void* d_ws,
                              size_t ws_size, hipStream_t stream) {
  const float* x  = (const float*)d_in[0];
  const int* erow = (const int*)d_in[1];
  const int* ecol = (const int*)d_in[2];
  const float* ew = (const float*)d_in[3];
  const float* W  = (const float*)d_in[4];
  const float* b  = (const float*)d_in[5];
  float* out      = (float*)d_out;

  const int N = in_sizes[0] / DIM;
  const int E = in_sizes[1];
  const int NB = (N + 1023) / 1024;

  char* wsp = (char*)d_ws;
  unsigned short* hb = (unsigned short*)wsp;  wsp += (size_t)N * DIM * sizeof(unsigned short);
  int*   off  = (int*)wsp;                    wsp += (size_t)N * sizeof(int);
  int*   pos  = (int*)wsp;                    wsp += (size_t)N * sizeof(int);
  int*   deg  = (int*)wsp;                    wsp += (size_t)N * sizeof(int);
  int*   bsum = (int*)wsp;                    wsp += 4096;
  unsigned short* Wb = (unsigned short*)wsp;  wsp += DIM * DIM * sizeof(unsigned short);
  int2*  sedge= (int2*)wsp;                   wsp += (size_t)E * sizeof(int2);

  conv_W<<<(DIM * DIM + 255) / 256, 256, 0, stream>>>(W, Wb);
  gemm_mfma<<<(N + 63) / 64, 256, 0, stream>>>(x, Wb, b, hb, N);

  hipMemsetAsync(deg, 0, (size_t)N * sizeof(int), stream);
  hist_rows<<<(E + 255) / 256, 256, 0, stream>>>(erow, deg, E);
  scan_blocks<<<NB, 256, 0, stream>>>(deg, off, bsum, N);
  scan_bsum<<<1, 256, 0, stream>>>(bsum, NB);
  add_base<<<(N + 255) / 256, 256, 0, stream>>>(off, pos, bsum, N);

  const int chunk = (N + NPASS - 1) / NPASS;
  for (int p = 0; p < NPASS; ++p) {
    int lo = p * chunk;
    int hi = (lo + chunk < N) ? lo + chunk : N;
    if (lo >= hi) break;
    scatter_csr_pass<<<(E + 255) / 256, 256, 0, stream>>>(erow, ecol, ew, pos,
                                                          sedge, E, lo, hi);
  }

  aggregate<<<(N * 64 + 255) / 256, 256, 0, stream>>>(hb, x, off, deg, sedge, out, N);
}

// Round 5
// 241.078 us; speedup vs baseline: 1.3195x; 1.3195x over previous
//
#include <hip/hip_runtime.h>

#define DIM 128
#define SB_SHIFT 9        // 512 rows per superbucket
#define SB_ROWS 512
#define TILE1 4096        // edges per part1 block

typedef short bf16x8 __attribute__((ext_vector_type(8)));
typedef float f32x4  __attribute__((ext_vector_type(4)));

__device__ inline unsigned short f2b(float f) {  // fp32 -> bf16 RNE
  unsigned int u = __float_as_uint(f);
  unsigned int r = u + 0x7FFFu + ((u >> 16) & 1u);
  return (unsigned short)(r >> 16);
}

// ================= W -> bf16 convert (once per launch) =====================
__global__ __launch_bounds__(256) void conv_W(const float* __restrict__ W,
                                              unsigned short* __restrict__ Wb) {
  int i = blockIdx.x * 256 + threadIdx.x;
  if (i < DIM * DIM) Wb[i] = f2b(W[i]);
}

// ================= GEMM: hb = bf16(x @ W^T + b), MFMA ======================
__global__ __launch_bounds__(256) void gemm_mfma(
    const float* __restrict__ x, const unsigned short* __restrict__ Wb,
    const float* __restrict__ b, unsigned short* __restrict__ hb, int N) {
  const int wid  = threadIdx.x >> 6;
  const int lane = threadIdx.x & 63;
  const int m0   = blockIdx.x * 64 + wid * 16;
  const int mrow = m0 + (lane & 15);
  const int koff = (lane >> 4) * 8;
  const int arow = (mrow < N) ? mrow : 0;

  f32x4 acc[8];
#pragma unroll
  for (int j = 0; j < 8; ++j) acc[j] = (f32x4){0.f, 0.f, 0.f, 0.f};

#pragma unroll
  for (int k0 = 0; k0 < DIM; k0 += 32) {
    const float* xp = x + (size_t)arow * DIM + k0 + koff;
    float4 a0 = *reinterpret_cast<const float4*>(xp);
    float4 a1 = *reinterpret_cast<const float4*>(xp + 4);
    bf16x8 af;
    af[0] = (short)f2b(a0.x); af[1] = (short)f2b(a0.y);
    af[2] = (short)f2b(a0.z); af[3] = (short)f2b(a0.w);
    af[4] = (short)f2b(a1.x); af[5] = (short)f2b(a1.y);
    af[6] = (short)f2b(a1.z); af[7] = (short)f2b(a1.w);
#pragma unroll
    for (int j = 0; j < 8; ++j) {
      const unsigned short* wp = Wb + (size_t)(j * 16 + (lane & 15)) * DIM + k0 + koff;
      bf16x8 bf = *reinterpret_cast<const bf16x8*>(wp);
      acc[j] = __builtin_amdgcn_mfma_f32_16x16x32_bf16(af, bf, acc[j], 0, 0, 0);
    }
  }

  const int rowbase = (lane >> 4) * 4;
#pragma unroll
  for (int j = 0; j < 8; ++j) {
    int n = j * 16 + (lane & 15);
    float bias = b[n];
#pragma unroll
    for (int i = 0; i < 4; ++i) {
      int m = m0 + rowbase + i;
      if (m < N) hb[(size_t)m * DIM + n] = f2b(acc[j][i] + bias);
    }
  }
}

// ======================= degree hist + scan ================================
__global__ __launch_bounds__(256) void hist_rows(const int* __restrict__ erow,
                                                 int* __restrict__ deg, int E) {
  int e = blockIdx.x * 256 + threadIdx.x;
  if (e < E) atomicAdd(&deg[erow[e]], 1);
}

__global__ __launch_bounds__(256) void scan_blocks(const int* __restrict__ deg,
                                                   int* __restrict__ off,
                                                   int* __restrict__ bsum, int N) {
  __shared__ int lds[256];
  const int base = blockIdx.x * 1024;
  const int t = threadIdx.x;
  int v[4], s = 0;
#pragma unroll
  for (int i = 0; i < 4; ++i) {
    int idx = base + t * 4 + i;
    v[i] = (idx < N) ? deg[idx] : 0;
    s += v[i];
  }
  lds[t] = s;
  __syncthreads();
  for (int d = 1; d < 256; d <<= 1) {
    int val = (t >= d) ? lds[t - d] : 0;
    __syncthreads();
    lds[t] += val;
    __syncthreads();
  }
  int incl = lds[t];
  int excl = incl - s;
  if (t == 255) bsum[blockIdx.x] = incl;
  int run = excl;
#pragma unroll
  for (int i = 0; i < 4; ++i) {
    int idx = base + t * 4 + i;
    if (idx < N) off[idx] = run;
    run += v[i];
  }
}

__global__ __launch_bounds__(256) void scan_bsum(int* __restrict__ bsum, int NB) {
  __shared__ int lds[256];
  const int t = threadIdx.x;
  int s = (t < NB) ? bsum[t] : 0;
  lds[t] = s;
  __syncthreads();
  for (int d = 1; d < 256; d <<= 1) {
    int val = (t >= d) ? lds[t - d] : 0;
    __syncthreads();
    lds[t] += val;
    __syncthreads();
  }
  if (t < NB) bsum[t] = lds[t] - s;  // exclusive
}

// Finalize off; seed superbucket cursors gcur[sb] = off[sb*512].
__global__ __launch_bounds__(256) void add_base(int* __restrict__ off,
                                                int* __restrict__ gcur,
                                                const int* __restrict__ bsum, int N) {
  int i = blockIdx.x * 256 + threadIdx.x;
  if (i < N) {
    int o = off[i] + bsum[i >> 10];
    off[i] = o;
    if ((i & (SB_ROWS - 1)) == 0) gcur[i >> SB_SHIFT] = o;
  }
}

// ============ part1: LDS-staged partition into superbuckets ================
// Packs edge -> (rowlo9<<17 | col, w) and writes bucket-contiguous runs
// (~21 edges avg) so global writes are near-full-line.
__global__ __launch_bounds__(256) void part1(
    const int* __restrict__ erow, const int* __restrict__ ecol,
    const float* __restrict__ ew, int* __restrict__ gcur,
    int2* __restrict__ gL1, int E, int NSB) {
  __shared__ int2 stage[TILE1];
  __shared__ unsigned short sbid[TILE1];
  __shared__ int lcnt[256], loff[256], gbs[256];

  const int t = threadIdx.x;
  const int base = blockIdx.x * TILE1;
  const int ntile = min(TILE1, E - base);

  for (int j = t; j < NSB; j += 256) lcnt[j] = 0;
  __syncthreads();

  int rk[TILE1 / 256];
#pragma unroll
  for (int i = 0; i < TILE1 / 256; ++i) {
    int e = base + t + i * 256;
    rk[i] = -1;
    if (e < E) {
      int bkt = erow[e] >> SB_SHIFT;
      rk[i] = atomicAdd(&lcnt[bkt], 1);
    }
  }
  __syncthreads();

  // Reserve global space per bucket; t0 builds local exclusive offsets.
  for (int j = t; j < NSB; j += 256) {
    int c = lcnt[j];
    if (c > 0) gbs[j] = atomicAdd(&gcur[j], c);
  }
  if (t == 0) {
    int run = 0;
    for (int j = 0; j < NSB; ++j) { loff[j] = run; run += lcnt[j]; }
  }
  __syncthreads();

#pragma unroll
  for (int i = 0; i < TILE1 / 256; ++i) {
    int e = base + t + i * 256;
    if (e < E) {
      int row = erow[e];
      int bkt = row >> SB_SHIFT;
      int slot = loff[bkt] + rk[i];
      stage[slot] = make_int2(((row & (SB_ROWS - 1)) << 17) | ecol[e],
                              __float_as_int(ew[e]));
      sbid[slot] = (unsigned short)bkt;
    }
  }
  __syncthreads();

  for (int s = t; s < ntile; s += 256) {
    int bkt = sbid[s];
    int dst = gbs[bkt] + (s - loff[bkt]);
    gL1[dst] = stage[s];
  }
}

// ============ part2: exact CSR placement within one superbucket ============
// One block per superbucket; row cursors live in LDS; all writes confined to
// this block's private sedge window -> single-XCD full-line writebacks.
__global__ __launch_bounds__(512) void part2(
    const int2* __restrict__ gL1, const int* __restrict__ off,
    int2* __restrict__ sedge, int N, int E) {
  __shared__ int cur[SB_ROWS];
  const int t = threadIdx.x;
  const int srow = blockIdx.x << SB_SHIFT;
  int row = srow + t;
  cur[t] = (row < N) ? off[row] : 0;
  __syncthreads();

  const int start = off[srow];
  const int nrow = srow + SB_ROWS;
  const int end = (nrow < N) ? off[nrow] : E;
  for (int i = start + t; i < end; i += 512) {
    int2 p = gL1[i];
    int rowlo = ((unsigned)p.x) >> 17;
    int dst = atomicAdd(&cur[rowlo], 1);
    sedge[dst] = make_int2(p.x & 0x1FFFF, p.y);
  }
}

// ============ Aggregate: out = lrelu(x + sum_e w*hb[col]) ==================
__global__ __launch_bounds__(256) void aggregate(
    const unsigned short* __restrict__ hb, const float* __restrict__ x,
    const int* __restrict__ off, const int* __restrict__ deg,
    const int2* __restrict__ sedge, float* __restrict__ out, int N) {
  int r = (blockIdx.x * 256 + threadIdx.x) >> 6;
  int lane = threadIdx.x & 63;
  if (r >= N) return;

  const int start = off[r];
  const int n = deg[r];
  float2 acc = make_float2(0.f, 0.f);
#pragma unroll 4
  for (int i = 0; i < n; ++i) {
    int2 e = sedge[start + i];
    float w = __int_as_float(e.y);
    unsigned int hv = *reinterpret_cast<const unsigned int*>(
        hb + (size_t)e.x * DIM + lane * 2);
    float h0 = __uint_as_float((hv & 0xFFFFu) << 16);
    float h1 = __uint_as_float((hv >> 16) << 16);
    acc.x += w * h0;
    acc.y += w * h1;
  }
  float2 xv = *reinterpret_cast<const float2*>(x + (size_t)r * DIM + lane * 2);
  float2 o = make_float2(acc.x + xv.x, acc.y + xv.y);
  o.x = o.x > 0.f ? o.x : 0.2f * o.x;
  o.y = o.y > 0.f ? o.y : 0.2f * o.y;
  *reinterpret_cast<float2*>(out + (size_t)r * DIM + lane * 2) = o;
}

// ===========================================================================
extern "C" void kernel_launch(void* const* d_in, const int* in_sizes, int n_in,
                              void* d_out, int out_size, void* d_ws,
                              size_t ws_size, hipStream_t stream) {
  const float* x  = (const float*)d_in[0];
  const int* erow = (const int*)d_in[1];
  const int* ecol = (const int*)d_in[2];
  const float* ew = (const float*)d_in[3];
  const float* W  = (const float*)d_in[4];
  const float* b  = (const float*)d_in[5];
  float* out      = (float*)d_out;

  const int N = in_sizes[0] / DIM;
  const int E = in_sizes[1];
  const int NB = (N + 1023) / 1024;
  const int NSB = (N + SB_ROWS - 1) >> SB_SHIFT;  // 196 for N=100000

  char* wsp = (char*)d_ws;
  unsigned short* hb = (unsigned short*)wsp;  wsp += (size_t)N * DIM * sizeof(unsigned short);
  int*   off  = (int*)wsp;                    wsp += (size_t)N * sizeof(int);
  int*   deg  = (int*)wsp;                    wsp += (size_t)N * sizeof(int);
  int*   bsum = (int*)wsp;                    wsp += 4096;
  int*   gcur = (int*)wsp;                    wsp += 4096;
  unsigned short* Wb = (unsigned short*)wsp;  wsp += DIM * DIM * sizeof(unsigned short);
  int2*  gL1  = (int2*)wsp;                   wsp += (size_t)E * sizeof(int2);
  int2*  sedge= (int2*)wsp;                   wsp += (size_t)E * sizeof(int2);

  conv_W<<<(DIM * DIM + 255) / 256, 256, 0, stream>>>(W, Wb);
  gemm_mfma<<<(N + 63) / 64, 256, 0, stream>>>(x, Wb, b, hb, N);

  hipMemsetAsync(deg, 0, (size_t)N * sizeof(int), stream);
  hist_rows<<<(E + 255) / 256, 256, 0, stream>>>(erow, deg, E);
  scan_blocks<<<NB, 256, 0, stream>>>(deg, off, bsum, N);
  scan_bsum<<<1, 256, 0, stream>>>(bsum, NB);
  add_base<<<(N + 255) / 256, 256, 0, stream>>>(off, gcur, bsum, N);

  part1<<<(E + TILE1 - 1) / TILE1, 256, 0, stream>>>(erow, ecol, ew, gcur,
                                                     gL1, E, NSB);
  part2<<<NSB, 512, 0, stream>>>(gL1, off, sedge, N, E);

  aggregate<<<(N * 64 + 255) / 256, 256, 0, stream>>>(hb, x, off, deg, sedge, out, N);
}

// Round 6
// 228.376 us; speedup vs baseline: 1.3929x; 1.0556x over previous
//
#include <hip/hip_runtime.h>

#define DIM 128
#define SB_SHIFT 9        // 512 rows per superbucket
#define SB_ROWS 512
#define TILE1 4096        // edges per part1 block

typedef short bf16x8 __attribute__((ext_vector_type(8)));
typedef float f32x4  __attribute__((ext_vector_type(4)));

__device__ inline unsigned short f2b(float f) {  // fp32 -> bf16 RNE
  unsigned int u = __float_as_uint(f);
  unsigned int r = u + 0x7FFFu + ((u >> 16) & 1u);
  return (unsigned short)(r >> 16);
}

// ================= W -> bf16 convert (once per launch) =====================
__global__ __launch_bounds__(256) void conv_W(const float* __restrict__ W,
                                              unsigned short* __restrict__ Wb) {
  int i = blockIdx.x * 256 + threadIdx.x;
  if (i < DIM * DIM) Wb[i] = f2b(W[i]);
}

// ================= GEMM: hb = bf16(x @ W^T + b), MFMA ======================
__global__ __launch_bounds__(256) void gemm_mfma(
    const float* __restrict__ x, const unsigned short* __restrict__ Wb,
    const float* __restrict__ b, unsigned short* __restrict__ hb, int N) {
  const int wid  = threadIdx.x >> 6;
  const int lane = threadIdx.x & 63;
  const int m0   = blockIdx.x * 64 + wid * 16;
  const int mrow = m0 + (lane & 15);
  const int koff = (lane >> 4) * 8;
  const int arow = (mrow < N) ? mrow : 0;

  f32x4 acc[8];
#pragma unroll
  for (int j = 0; j < 8; ++j) acc[j] = (f32x4){0.f, 0.f, 0.f, 0.f};

#pragma unroll
  for (int k0 = 0; k0 < DIM; k0 += 32) {
    const float* xp = x + (size_t)arow * DIM + k0 + koff;
    float4 a0 = *reinterpret_cast<const float4*>(xp);
    float4 a1 = *reinterpret_cast<const float4*>(xp + 4);
    bf16x8 af;
    af[0] = (short)f2b(a0.x); af[1] = (short)f2b(a0.y);
    af[2] = (short)f2b(a0.z); af[3] = (short)f2b(a0.w);
    af[4] = (short)f2b(a1.x); af[5] = (short)f2b(a1.y);
    af[6] = (short)f2b(a1.z); af[7] = (short)f2b(a1.w);
#pragma unroll
    for (int j = 0; j < 8; ++j) {
      const unsigned short* wp = Wb + (size_t)(j * 16 + (lane & 15)) * DIM + k0 + koff;
      bf16x8 bf = *reinterpret_cast<const bf16x8*>(wp);
      acc[j] = __builtin_amdgcn_mfma_f32_16x16x32_bf16(af, bf, acc[j], 0, 0, 0);
    }
  }

  const int rowbase = (lane >> 4) * 4;
#pragma unroll
  for (int j = 0; j < 8; ++j) {
    int n = j * 16 + (lane & 15);
    float bias = b[n];
#pragma unroll
    for (int i = 0; i < 4; ++i) {
      int m = m0 + rowbase + i;
      if (m < N) hb[(size_t)m * DIM + n] = f2b(acc[j][i] + bias);
    }
  }
}

// ======================= degree hist + scan ================================
__global__ __launch_bounds__(256) void hist_rows(const int* __restrict__ erow,
                                                 int* __restrict__ deg, int E) {
  int e = blockIdx.x * 256 + threadIdx.x;
  if (e < E) atomicAdd(&deg[erow[e]], 1);
}

__global__ __launch_bounds__(256) void scan_blocks(const int* __restrict__ deg,
                                                   int* __restrict__ off,
                                                   int* __restrict__ bsum, int N) {
  __shared__ int lds[256];
  const int base = blockIdx.x * 1024;
  const int t = threadIdx.x;
  int v[4], s = 0;
#pragma unroll
  for (int i = 0; i < 4; ++i) {
    int idx = base + t * 4 + i;
    v[i] = (idx < N) ? deg[idx] : 0;
    s += v[i];
  }
  lds[t] = s;
  __syncthreads();
  for (int d = 1; d < 256; d <<= 1) {
    int val = (t >= d) ? lds[t - d] : 0;
    __syncthreads();
    lds[t] += val;
    __syncthreads();
  }
  int incl = lds[t];
  int excl = incl - s;
  if (t == 255) bsum[blockIdx.x] = incl;
  int run = excl;
#pragma unroll
  for (int i = 0; i < 4; ++i) {
    int idx = base + t * 4 + i;
    if (idx < N) off[idx] = run;
    run += v[i];
  }
}

__global__ __launch_bounds__(256) void scan_bsum(int* __restrict__ bsum, int NB) {
  __shared__ int lds[256];
  const int t = threadIdx.x;
  int s = (t < NB) ? bsum[t] : 0;
  lds[t] = s;
  __syncthreads();
  for (int d = 1; d < 256; d <<= 1) {
    int val = (t >= d) ? lds[t - d] : 0;
    __syncthreads();
    lds[t] += val;
    __syncthreads();
  }
  if (t < NB) bsum[t] = lds[t] - s;  // exclusive
}

// Finalize off; seed superbucket cursors gcur[sb] = off[sb*512].
__global__ __launch_bounds__(256) void add_base(int* __restrict__ off,
                                                int* __restrict__ gcur,
                                                const int* __restrict__ bsum, int N) {
  int i = blockIdx.x * 256 + threadIdx.x;
  if (i < N) {
    int o = off[i] + bsum[i >> 10];
    off[i] = o;
    if ((i & (SB_ROWS - 1)) == 0) gcur[i >> SB_SHIFT] = o;
  }
}

// ============ part1: LDS-staged partition into superbuckets ================
__global__ __launch_bounds__(256) void part1(
    const int* __restrict__ erow, const int* __restrict__ ecol,
    const float* __restrict__ ew, int* __restrict__ gcur,
    int2* __restrict__ gL1, int E, int NSB) {
  __shared__ int2 stage[TILE1];
  __shared__ unsigned short sbid[TILE1];
  __shared__ int lcnt[256], loff[256], gbs[256], stmp[256];

  const int t = threadIdx.x;
  const int base = blockIdx.x * TILE1;
  const int ntile = min(TILE1, E - base);

  lcnt[t] = 0;
  __syncthreads();

  int rk[TILE1 / 256];
#pragma unroll
  for (int i = 0; i < TILE1 / 256; ++i) {
    int e = base + t + i * 256;
    rk[i] = -1;
    if (e < E) {
      int bkt = erow[e] >> SB_SHIFT;
      rk[i] = atomicAdd(&lcnt[bkt], 1);
    }
  }
  __syncthreads();

  // Parallel exclusive scan of lcnt -> loff; reserve global space per bucket.
  int myc = lcnt[t];
  stmp[t] = myc;
  __syncthreads();
  for (int d = 1; d < 256; d <<= 1) {
    int val = (t >= d) ? stmp[t - d] : 0;
    __syncthreads();
    stmp[t] += val;
    __syncthreads();
  }
  loff[t] = stmp[t] - myc;
  if (t < NSB && myc > 0) gbs[t] = atomicAdd(&gcur[t], myc);
  __syncthreads();

#pragma unroll
  for (int i = 0; i < TILE1 / 256; ++i) {
    int e = base + t + i * 256;
    if (e < E) {
      int row = erow[e];
      int bkt = row >> SB_SHIFT;
      int slot = loff[bkt] + rk[i];
      stage[slot] = make_int2(((row & (SB_ROWS - 1)) << 17) | ecol[e],
                              __float_as_int(ew[e]));
      sbid[slot] = (unsigned short)bkt;
    }
  }
  __syncthreads();

  for (int s = t; s < ntile; s += 256) {
    int bkt = sbid[s];
    int dst = gbs[bkt] + (s - loff[bkt]);
    gL1[dst] = stage[s];
  }
}

// ============ part2: exact CSR placement within one superbucket ============
__global__ __launch_bounds__(512) void part2(
    const int2* __restrict__ gL1, const int* __restrict__ off,
    int2* __restrict__ sedge, int N, int E) {
  __shared__ int cur[SB_ROWS];
  const int t = threadIdx.x;
  const int srow = blockIdx.x << SB_SHIFT;
  int row = srow + t;
  cur[t] = (row < N) ? off[row] : 0;
  __syncthreads();

  const int start = off[srow];
  const int nrow = srow + SB_ROWS;
  const int end = (nrow < N) ? off[nrow] : E;
  for (int i = start + t; i < end; i += 512) {
    int2 p = gL1[i];
    int rowlo = ((unsigned)p.x) >> 17;
    int dst = atomicAdd(&cur[rowlo], 1);
    sedge[dst] = make_int2(p.x & 0x1FFFF, p.y);
  }
}

// ============ Aggregate: out = lrelu(x + sum_e w*hb[col]) ==================
// 16 lanes per row (dwordx4 = 8 bf16 per lane), 4 rows per wave, 16 rows per
// 256-block. Edge loop unrolled 4-deep: 4 sedge loads + 4 row-gathers in
// flight before any consume -> ~4KB outstanding per wave (latency fix).
__global__ __launch_bounds__(256) void aggregate(
    const unsigned short* __restrict__ hb, const float* __restrict__ x,
    const int* __restrict__ off, const int* __restrict__ deg,
    const int2* __restrict__ sedge, float* __restrict__ out, int N) {
  const int r  = (blockIdx.x * 256 + threadIdx.x) >> 4;  // row per 16-lane group
  const int l  = threadIdx.x & 15;                       // lane within group
  if (r >= N) return;

  const int start = off[r];
  const int n = deg[r];
  const size_t rowb = (size_t)r * DIM + l * 8;  // elem offset (8 elems/lane)

  // acc starts from residual x
  float acc[8];
  {
    float4 x0 = *reinterpret_cast<const float4*>(x + rowb);
    float4 x1 = *reinterpret_cast<const float4*>(x + rowb + 4);
    acc[0] = x0.x; acc[1] = x0.y; acc[2] = x0.z; acc[3] = x0.w;
    acc[4] = x1.x; acc[5] = x1.y; acc[6] = x1.z; acc[7] = x1.w;
  }

#define GATHER(ee) (*reinterpret_cast<const uint4*>(hb + (size_t)(ee).x * DIM + l * 8))
#define ACCUM(hv, wv)                                                      \
  {                                                                        \
    float w_ = (wv);                                                       \
    acc[0] += w_ * __uint_as_float(((hv).x & 0xFFFFu) << 16);              \
    acc[1] += w_ * __uint_as_float(((hv).x >> 16) << 16);                  \
    acc[2] += w_ * __uint_as_float(((hv).y & 0xFFFFu) << 16);              \
    acc[3] += w_ * __uint_as_float(((hv).y >> 16) << 16);                  \
    acc[4] += w_ * __uint_as_float(((hv).z & 0xFFFFu) << 16);              \
    acc[5] += w_ * __uint_as_float(((hv).z >> 16) << 16);                  \
    acc[6] += w_ * __uint_as_float(((hv).w & 0xFFFFu) << 16);              \
    acc[7] += w_ * __uint_as_float(((hv).w >> 16) << 16);                  \
  }

  int j = 0;
  for (; j + 4 <= n; j += 4) {
    int2 e0 = sedge[start + j];
    int2 e1 = sedge[start + j + 1];
    int2 e2 = sedge[start + j + 2];
    int2 e3 = sedge[start + j + 3];
    uint4 h0 = GATHER(e0);
    uint4 h1 = GATHER(e1);
    uint4 h2 = GATHER(e2);
    uint4 h3 = GATHER(e3);
    ACCUM(h0, __int_as_float(e0.y));
    ACCUM(h1, __int_as_float(e1.y));
    ACCUM(h2, __int_as_float(e2.y));
    ACCUM(h3, __int_as_float(e3.y));
  }
  for (; j < n; ++j) {
    int2 e = sedge[start + j];
    uint4 hv = GATHER(e);
    ACCUM(hv, __int_as_float(e.y));
  }
#undef GATHER
#undef ACCUM

  float4 o0, o1;
  o0.x = acc[0] > 0.f ? acc[0] : 0.2f * acc[0];
  o0.y = acc[1] > 0.f ? acc[1] : 0.2f * acc[1];
  o0.z = acc[2] > 0.f ? acc[2] : 0.2f * acc[2];
  o0.w = acc[3] > 0.f ? acc[3] : 0.2f * acc[3];
  o1.x = acc[4] > 0.f ? acc[4] : 0.2f * acc[4];
  o1.y = acc[5] > 0.f ? acc[5] : 0.2f * acc[5];
  o1.z = acc[6] > 0.f ? acc[6] : 0.2f * acc[6];
  o1.w = acc[7] > 0.f ? acc[7] : 0.2f * acc[7];
  *reinterpret_cast<float4*>(out + rowb)     = o0;
  *reinterpret_cast<float4*>(out + rowb + 4) = o1;
}

// ===========================================================================
extern "C" void kernel_launch(void* const* d_in, const int* in_sizes, int n_in,
                              void* d_out, int out_size, void* d_ws,
                              size_t ws_size, hipStream_t stream) {
  const float* x  = (const float*)d_in[0];
  const int* erow = (const int*)d_in[1];
  const int* ecol = (const int*)d_in[2];
  const float* ew = (const float*)d_in[3];
  const float* W  = (const float*)d_in[4];
  const float* b  = (const float*)d_in[5];
  float* out      = (float*)d_out;

  const int N = in_sizes[0] / DIM;
  const int E = in_sizes[1];
  const int NB = (N + 1023) / 1024;
  const int NSB = (N + SB_ROWS - 1) >> SB_SHIFT;  // 196 for N=100000

  char* wsp = (char*)d_ws;
  unsigned short* hb = (unsigned short*)wsp;  wsp += (size_t)N * DIM * sizeof(unsigned short);
  int*   off  = (int*)wsp;                    wsp += (size_t)N * sizeof(int);
  int*   deg  = (int*)wsp;                    wsp += (size_t)N * sizeof(int);
  int*   bsum = (int*)wsp;                    wsp += 4096;
  int*   gcur = (int*)wsp;                    wsp += 4096;
  unsigned short* Wb = (unsigned short*)wsp;  wsp += DIM * DIM * sizeof(unsigned short);
  int2*  gL1  = (int2*)wsp;                   wsp += (size_t)E * sizeof(int2);
  int2*  sedge= (int2*)wsp;                   wsp += (size_t)E * sizeof(int2);

  conv_W<<<(DIM * DIM + 255) / 256, 256, 0, stream>>>(W, Wb);
  gemm_mfma<<<(N + 63) / 64, 256, 0, stream>>>(x, Wb, b, hb, N);

  hipMemsetAsync(deg, 0, (size_t)N * sizeof(int), stream);
  hist_rows<<<(E + 255) / 256, 256, 0, stream>>>(erow, deg, E);
  scan_blocks<<<NB, 256, 0, stream>>>(deg, off, bsum, N);
  scan_bsum<<<1, 256, 0, stream>>>(bsum, NB);
  add_base<<<(N + 255) / 256, 256, 0, stream>>>(off, gcur, bsum, N);

  part1<<<(E + TILE1 - 1) / TILE1, 256, 0, stream>>>(erow, ecol, ew, gcur,
                                                     gL1, E, NSB);
  part2<<<NSB, 512, 0, stream>>>(gL1, off, sedge, N, E);

  // 16 rows per 256-thread block
  aggregate<<<(N + 15) / 16, 256, 0, stream>>>(hb, x, off, deg, sedge, out, N);
}